// Round 6
// baseline (488.168 us; speedup 1.0000x reference)
//
#include <hip/hip_runtime.h>
#include <hip/hip_bf16.h>
#include <math.h>

#define B_SZ 1024
#define NMAX 21
#define NN 441            // 21*21
#define HNF 256
#define TOT_ROWS (B_SZ * NN)   // 451584
#define TILES_PER_BATCH 7      // 441 = 7*63
#define BMV 63                 // valid rows per tile (row 63 is pad)

typedef short short8 __attribute__((ext_vector_type(8)));
typedef float float4v __attribute__((ext_vector_type(4)));

__device__ __forceinline__ float softplus_f(float x) {
    return fmaxf(x, 0.f) + log1pf(expf(-fabsf(x)));
}

__device__ __forceinline__ unsigned short f2bf(float x) {
    union { float f; unsigned int u; } v; v.f = x;
    unsigned int r = v.u + 0x7FFFu + ((v.u >> 16) & 1u);   // RNE
    return (unsigned short)(r >> 16);
}

// hardware packed fp32->bf16 (v_cvt_pk_bf16_f32), RNE
__device__ __forceinline__ unsigned pk_bf16(float lo, float hi) {
    __hip_bfloat162 h = __float22bfloat162_rn(float2{lo, hi});
    return *reinterpret_cast<unsigned*>(&h);
}

// wave-uniform broadcast of lane q via SGPR (readlane), avoids ds_bpermute
__device__ __forceinline__ float bcast(float v, int q) {
    int i = __builtin_amdgcn_readlane(__builtin_bit_cast(int, v), q);
    return __builtin_bit_cast(float, i);
}

// ---------------------------------------------------------------------------
// Pack W1 into MFMA B-fragment order as bf16.
// Fragment (kstep s 0..7, nfrag f 0..15): lane l, elem j holds
// W1[s*32 + (l>>4)*8 + j][f*16 + (l&15)].  Linear idx = ((s*16+f)*64+l)*8+j.
// ---------------------------------------------------------------------------
__global__ __launch_bounds__(256) void pack_w1(const float* __restrict__ W1,
                                               short* __restrict__ B0p)
{
    int id = blockIdx.x * 256 + threadIdx.x;   // 0..65535
    int j = id & 7, l = (id >> 3) & 63, f = (id >> 9) & 15, s = id >> 13;
    int k = s * 32 + ((l >> 4) << 3) + j;
    int c = (f << 4) + (l & 15);
    B0p[id] = (short)f2bf(W1[k * HNF + c]);
}

// ---------------------------------------------------------------------------
// Kernel 1: 7168 blocks x 512 threads (8 waves). One 64x256 tile per block
// (63 valid rows). Each thread stages 8 float4 (row t>>3, float4 i -> kstep
// i), converts to bf16, writes fragment-linear LDS; ONE barrier; barrier-free
// MFMA loop: wave w owns n-frags {2w, 2w+1} -> 64 MFMA/wave. Fused epilogue:
// bias+relu, e2 row-dots -> raw D/W, emb partials via atomics.
// Occupancy: 32KB+4KB LDS -> 4 blocks/CU x 8 waves = 32 waves/CU.
// ---------------------------------------------------------------------------
__global__ __launch_bounds__(512, 8) void fused_mlp_bf16(
    const float* __restrict__ gnn, const short* __restrict__ B0p,
    const float* __restrict__ b1, const float* __restrict__ W2,
    const float* __restrict__ b2,
    float* __restrict__ Dreg, float* __restrict__ Wreg, float* __restrict__ emb)
{
    __shared__ short Abf[16384];      // 32KB frag-linear: ((kk*4+m)*64+l)*8
    __shared__ float red0[8][64];
    __shared__ float red1[8][64];

    const int t = threadIdx.x;
    const int w = t >> 6, l = t & 63;
    const int batch = blockIdx.x / TILES_PER_BATCH;
    const int tile  = blockIdx.x % TILES_PER_BATCH;
    const long row0 = (long)batch * NN + (long)tile * BMV;

    // ---- staging mapping: row r = t>>3, col chunk cq = t&7 ----
    const int r  = t >> 3;       // 0..63
    const int cq = t & 7;        // 0..7
    long ar = row0 + r;
    if (ar >= (long)TOT_ROWS) ar = TOT_ROWS - 1;   // pad row of last block
    const float* asrc = gnn + ar * HNF + (cq << 2);

    // fragment decode for compute
    const int frow = l & 15;
    const int fk   = l >> 4;

    // ---- prologue: 8 independent float4 loads (32 VGPR in flight) ----
    float4 fr[8];
    #pragma unroll
    for (int i = 0; i < 8; i++)
        fr[i] = *(const float4*)(asrc + (i << 5));

    // float4 i covers cols 4*cq + 32*i .. +3  ->  kstep kk = i exactly
    const int m_s   = r >> 4;
    const int lslot = ((cq >> 1) << 4) | (r & 15);   // fragment lane slot
    #pragma unroll
    for (int i = 0; i < 8; i++) {
        uint2 pv;
        pv.x = pk_bf16(fr[i].x, fr[i].y);
        pv.y = pk_bf16(fr[i].z, fr[i].w);
        int sbase = (((((i << 2) + m_s) << 6) | lslot) << 3) + ((cq & 1) << 2);
        *(uint2*)(Abf + sbase) = pv;
    }
    __syncthreads();

    // ---- barrier-free MFMA loop: 8 k-steps x (4m x 2n) per wave ----
    float4v acc[4][2];
    #pragma unroll
    for (int m = 0; m < 4; m++)
        #pragma unroll
        for (int n = 0; n < 2; n++)
            acc[m][n] = (float4v){0.f, 0.f, 0.f, 0.f};

    #pragma unroll 2
    for (int kk = 0; kk < 8; ++kk) {
        short8 bf[2], af[4];
        #pragma unroll
        for (int n = 0; n < 2; n++) {
            int nf = (w << 1) + n;
            size_t off = (size_t)((((kk << 4) + nf) << 6) | l) << 3;
            bf[n] = *(const short8*)(B0p + off);
        }
        #pragma unroll
        for (int m = 0; m < 4; m++)
            af[m] = *(const short8*)(Abf + ((((kk << 2) + m) << 6) | l) * 8);
        #pragma unroll
        for (int m = 0; m < 4; m++)
            #pragma unroll
            for (int n = 0; n < 2; n++)
                acc[m][n] = __builtin_amdgcn_mfma_f32_16x16x32_bf16(af[m], bf[n], acc[m][n], 0, 0, 0);
    }

    // ---- epilogue: bias+relu, e2 row-dots, emb partials ----
    // C frag layout: col = (2w+n)*16 + (l&15), row = m*16 + (l>>4)*4 + j
    float w20[2], w21[2], b1v[2];
    #pragma unroll
    for (int n = 0; n < 2; n++) {
        int c = (((w << 1) + n) << 4) + frow;
        b1v[n] = b1[c];
        w20[n] = W2[2 * c];
        w21[n] = W2[2 * c + 1];
    }
    float ps0[4][4], ps1[4][4], embp[2] = {0.f, 0.f};
    #pragma unroll
    for (int m = 0; m < 4; m++)
        #pragma unroll
        for (int j = 0; j < 4; j++) { ps0[m][j] = 0.f; ps1[m][j] = 0.f; }

    #pragma unroll
    for (int m = 0; m < 4; m++)
        #pragma unroll
        for (int n = 0; n < 2; n++)
            #pragma unroll
            for (int j = 0; j < 4; j++) {
                float h = fmaxf(acc[m][n][j] + b1v[n], 0.f);
                ps0[m][j] += h * w20[n];
                ps1[m][j] += h * w21[n];
                int row = (m << 4) + (fk << 2) + j;
                if (row < BMV) embp[n] += h;     // exclude pad row
            }

    #pragma unroll
    for (int off = 1; off < 16; off <<= 1)
        #pragma unroll
        for (int m = 0; m < 4; m++)
            #pragma unroll
            for (int j = 0; j < 4; j++) {
                ps0[m][j] += __shfl_xor(ps0[m][j], off);
                ps1[m][j] += __shfl_xor(ps1[m][j], off);
            }
    if (frow == 0) {
        #pragma unroll
        for (int m = 0; m < 4; m++)
            #pragma unroll
            for (int j = 0; j < 4; j++) {
                int row = (m << 4) + (fk << 2) + j;
                red0[w][row] = ps0[m][j];
                red1[w][row] = ps1[m][j];
            }
    }

    #pragma unroll
    for (int n = 0; n < 2; n++) {
        embp[n] += __shfl_xor(embp[n], 16);
        embp[n] += __shfl_xor(embp[n], 32);
    }
    if (l < 16) {
        #pragma unroll
        for (int n = 0; n < 2; n++)
            atomicAdd(emb + (size_t)batch * 256 + (((w << 1) + n) << 4) + l, embp[n]);
    }

    __syncthreads();
    if (t < BMV) {
        float v0 = b2[0], v1 = b2[1];
        #pragma unroll
        for (int ww = 0; ww < 8; ww++) { v0 += red0[ww][t]; v1 += red1[ww][t]; }
        Dreg[row0 + t] = v0;    // raw e2 ch0 (symmetrized in recon)
        Wreg[row0 + t] = v1;
    }
}

// ---------------------------------------------------------------------------
// Kernel 2: fused symmetrize+softplus (writes D/W outputs) + register MDS
// recon. 1 block = 1 wave = 1 batch; lane i<21 owns row i. All wave-uniform
// broadcasts via readlane (SGPR), not ds_bpermute.
// ---------------------------------------------------------------------------
__global__ __launch_bounds__(64) void symrecon_kernel(
    float* __restrict__ Dreg, float* __restrict__ Wreg,
    const float* __restrict__ un, const float* __restrict__ xn,
    float* __restrict__ Xo)
{
    const int b = blockIdx.x, l = threadIdx.x;
    __shared__ float R0[NN], R1[NN];

    float* Db = Dreg + (size_t)b * NN;
    float* Wb = Wreg + (size_t)b * NN;
    for (int idx = l; idx < NN; idx += 64) { R0[idx] = Db[idx]; R1[idx] = Wb[idx]; }
    __syncthreads();

    const bool act = (l < NMAX);
    const int li = act ? l : 0;
    float Drow[NMAX], Wrow[NMAX];
    float rs = 0.f;
    #pragma unroll
    for (int q = 0; q < NMAX; q++) {
        float rd = R0[li * NMAX + q] + R0[q * NMAX + li];
        float rw = R1[li * NMAX + q] + R1[q * NMAX + li];
        float d = (q == li) ? 0.f : softplus_f(rd);
        float wv = softplus_f(rw);
        Drow[q] = act ? d : 0.f;
        Wrow[q] = act ? wv : 0.f;
        rs += Drow[q];
    }
    if (act) {
        #pragma unroll
        for (int q = 0; q < NMAX; q++) {
            Db[l * NMAX + q] = Drow[q];
            Wb[l * NMAX + q] = Wrow[q];
        }
    }

    // double-centering -> A rows in registers
    float tot = rs;
    #pragma unroll
    for (int m = 1; m < 64; m <<= 1) tot += __shfl_xor(tot, m);
    const float mean = tot * (1.f / (float)NN);
    const float rsn = rs * (1.f / (float)NMAX);
    float Arow[NMAX];
    #pragma unroll
    for (int q = 0; q < NMAX; q++) {
        float rsq = bcast(rsn, q);
        float v = -0.5f * (Drow[q] - rsn - rsq + mean);
        Arow[q] = act ? v : 0.f;
    }

    // deflated power iteration: k=3 eigvecs, 10 steps each
    float xr[3] = {0.f, 0.f, 0.f};
    #pragma unroll
    for (int e = 0; e < 3; e++) {
        float u = act ? un[(size_t)b * 63 + e * NMAX + l] : 0.f;
        for (int s = 0; s < 10; s++) {
            float n2 = u * u;
            #pragma unroll
            for (int m = 1; m < 64; m <<= 1) n2 += __shfl_xor(n2, m);
            u *= 1.f / fmaxf(sqrtf(n2), 1e-3f);
            float a = 0.f;
            #pragma unroll
            for (int q = 0; q < NMAX; q++) a = fmaf(Arow[q], bcast(u, q), a);
            u = act ? a : 0.f;
        }
        float e2 = u * u;
        #pragma unroll
        for (int m = 1; m < 64; m <<= 1) e2 += __shfl_xor(e2, m);
        u *= 1.f / sqrtf(sqrtf(e2 + 0.01f));
        xr[e] = u;
        #pragma unroll
        for (int q = 0; q < NMAX; q++) Arow[q] = fmaf(-u, bcast(u, q), Arow[q]);
    }
    float x = xr[0], y = xr[1], z = xr[2];
    if (act) {
        x += xn[(size_t)b * 63 + l * 3 + 0];
        y += xn[(size_t)b * 63 + l * 3 + 1];
        z += xn[(size_t)b * 63 + l * 3 + 2];
    }

    // 100 clipped gradient-descent steps (registers + readlane broadcasts)
    for (int tstep = 0; tstep < 100; tstep++) {
        float gx = 0.f, gy = 0.f, gz = 0.f;
        #pragma unroll
        for (int q = 0; q < NMAX; q++) {
            float dx = x - bcast(x, q);
            float dy = y - bcast(y, q);
            float dz = z - bcast(z, q);
            float s = fmaf(dx, dx, fmaf(dy, dy, fmaf(dz, dz, 0.01f)));
            float cm = Wrow[q] * (Drow[q] - s);
            gx = fmaf(cm, dx, gx);
            gy = fmaf(cm, dy, gy);
            gz = fmaf(cm, dz, gz);
        }
        float d0 = 0.8f * gx, d1 = 0.8f * gy, d2 = 0.8f * gz;
        float speed = sqrtf(fmaf(d0, d0, fmaf(d1, d1, fmaf(d2, d2, 1e-3f))));
        float alpha = 0.1f + 4.9f * (100.f - (float)tstep) * 0.01f;
        float scale = alpha * tanhf(speed / alpha) / speed;
        x = fmaf(d0, scale, x);
        y = fmaf(d1, scale, y);
        z = fmaf(d2, scale, z);
    }
    if (act) {
        Xo[(size_t)b * 63 + l * 3 + 0] = x;
        Xo[(size_t)b * 63 + l * 3 + 1] = y;
        Xo[(size_t)b * 63 + l * 3 + 2] = z;
    }
}

// ---------------------------------------------------------------------------
extern "C" void kernel_launch(void* const* d_in, const int* in_sizes, int n_in,
                              void* d_out, int out_size, void* d_ws, size_t ws_size,
                              hipStream_t stream) {
    const float* gnn = (const float*)d_in[0];
    const float* W1  = (const float*)d_in[1];
    const float* b1  = (const float*)d_in[2];
    const float* W2  = (const float*)d_in[3];
    const float* b2  = (const float*)d_in[4];
    const float* un  = (const float*)d_in[5];
    const float* xn  = (const float*)d_in[6];

    float* out  = (float*)d_out;
    float* Dreg = out;                                  // [1024*441]
    float* Wreg = out + (size_t)TOT_ROWS;               // [1024*441]
    float* emb  = out + (size_t)2 * TOT_ROWS;           // [1024*256]
    float* Xo   = out + (size_t)2 * TOT_ROWS + B_SZ*256;// [1024*63]

    short* B0p = (short*)d_ws;                          // 65536 bf16 (128KB)

    pack_w1<<<dim3(256), dim3(256), 0, stream>>>(W1, B0p);
    hipMemsetAsync(emb, 0, (size_t)B_SZ * 256 * sizeof(float), stream);

    fused_mlp_bf16<<<dim3(B_SZ * TILES_PER_BATCH), dim3(512), 0, stream>>>(
        gnn, B0p, b1, W2, b2, Dreg, Wreg, emb);

    symrecon_kernel<<<dim3(B_SZ), dim3(64), 0, stream>>>(Dreg, Wreg, un, xn, Xo);
}

// Round 7
// 482.075 us; speedup vs baseline: 1.0126x; 1.0126x over previous
//
#include <hip/hip_runtime.h>
#include <hip/hip_bf16.h>
#include <math.h>

#define B_SZ 1024
#define NMAX 21
#define NN 441            // 21*21
#define HNF 256
#define TOT_ROWS (B_SZ * NN)   // 451584
#define TILES_PER_BATCH 7      // 441 = 7*63
#define BMV 63                 // valid rows per tile (row 63 is pad)

typedef short short8 __attribute__((ext_vector_type(8)));
typedef float float4v __attribute__((ext_vector_type(4)));

__device__ __forceinline__ float softplus_f(float x) {
    return fmaxf(x, 0.f) + log1pf(expf(-fabsf(x)));
}

__device__ __forceinline__ unsigned short f2bf(float x) {
    union { float f; unsigned int u; } v; v.f = x;
    unsigned int r = v.u + 0x7FFFu + ((v.u >> 16) & 1u);   // RNE
    return (unsigned short)(r >> 16);
}

// hardware packed fp32->bf16 (v_cvt_pk_bf16_f32), RNE
__device__ __forceinline__ unsigned pk_bf16(float lo, float hi) {
    __hip_bfloat162 h = __float22bfloat162_rn(float2{lo, hi});
    return *reinterpret_cast<unsigned*>(&h);
}

// wave-uniform broadcast of lane q via SGPR (readlane), avoids ds_bpermute
__device__ __forceinline__ float bcast(float v, int q) {
    int i = __builtin_amdgcn_readlane(__builtin_bit_cast(int, v), q);
    return __builtin_bit_cast(float, i);
}

// ---------------------------------------------------------------------------
// Pack W1 into MFMA B-fragment order as bf16.
// Fragment (kstep s 0..7, nfrag f 0..15): lane l, elem j holds
// W1[s*32 + (l>>4)*8 + j][f*16 + (l&15)].  Linear idx = ((s*16+f)*64+l)*8+j.
// ---------------------------------------------------------------------------
__global__ __launch_bounds__(256) void pack_w1(const float* __restrict__ W1,
                                               short* __restrict__ B0p)
{
    int id = blockIdx.x * 256 + threadIdx.x;   // 0..65535
    int j = id & 7, l = (id >> 3) & 63, f = (id >> 9) & 15, s = id >> 13;
    int k = s * 32 + ((l >> 4) << 3) + j;
    int c = (f << 4) + (l & 15);
    B0p[id] = (short)f2bf(W1[k * HNF + c]);
}

// ---------------------------------------------------------------------------
// Kernel 1: 3584 blocks x 512 threads (8 waves); each block processes TWO
// consecutive 64x256 tiles (63 valid rows each) with register prefetch:
// tile i+1's global loads are issued right after tile i's LDS write, so HBM
// latency hides under tile i's MFMA + epilogue. Single 32KB LDS buffer
// (barrier ordering makes overwrite safe). Wave w owns n-frags {2w, 2w+1}.
// Fused epilogue: bias+relu, e2 row-dots -> raw D/W, emb partials (atomics).
// ---------------------------------------------------------------------------
__global__ __launch_bounds__(512, 4) void fused_mlp_bf16(
    const float* __restrict__ gnn, const short* __restrict__ B0p,
    const float* __restrict__ b1, const float* __restrict__ W2,
    const float* __restrict__ b2,
    float* __restrict__ Dreg, float* __restrict__ Wreg, float* __restrict__ emb)
{
    __shared__ short Abf[16384];      // 32KB frag-linear: ((kk*4+m)*64+l)*8
    __shared__ float red0[8][64];
    __shared__ float red1[8][64];

    const int t = threadIdx.x;
    const int w = t >> 6, l = t & 63;

    // staging decode: row r = t>>3 (0..63), col chunk cq = t&7
    const int r  = t >> 3;
    const int cq = t & 7;
    const int m_s   = r >> 4;
    const int lslot = ((cq >> 1) << 4) | (r & 15);

    // fragment decode
    const int frow = l & 15;
    const int fk   = l >> 4;

    // invariant epilogue weights
    float w20[2], w21[2], b1v[2];
    #pragma unroll
    for (int n = 0; n < 2; n++) {
        int c = (((w << 1) + n) << 4) + frow;
        b1v[n] = b1[c];
        w20[n] = W2[2 * c];
        w21[n] = W2[2 * c + 1];
    }
    const float b20 = b2[0], b21 = b2[1];

    // ---- load tile 0 into registers ----
    float4 fr[8];
    {
        const int tau = blockIdx.x * 2;
        const long row0 = (long)(tau / TILES_PER_BATCH) * NN
                        + (long)(tau % TILES_PER_BATCH) * BMV;
        long ar = row0 + r;
        if (ar >= (long)TOT_ROWS) ar = TOT_ROWS - 1;
        const float* asrc = gnn + ar * HNF + (cq << 2);
        #pragma unroll
        for (int i = 0; i < 8; i++)
            fr[i] = *(const float4*)(asrc + (i << 5));
    }

    for (int p = 0; p < 2; ++p) {
        const int tau = blockIdx.x * 2 + p;
        const long row0 = (long)(tau / TILES_PER_BATCH) * NN
                        + (long)(tau % TILES_PER_BATCH) * BMV;

        // ---- convert fp32 -> bf16, write fragment-linear LDS ----
        #pragma unroll
        for (int i = 0; i < 8; i++) {
            uint2 pv;
            pv.x = pk_bf16(fr[i].x, fr[i].y);
            pv.y = pk_bf16(fr[i].z, fr[i].w);
            int sbase = (((((i << 2) + m_s) << 6) | lslot) << 3) + ((cq & 1) << 2);
            *(uint2*)(Abf + sbase) = pv;
        }
        __syncthreads();

        // ---- prefetch tile 1 (loads fly during MFMA + epilogue) ----
        if (p == 0) {
            const int tau1 = tau + 1;
            const long row1 = (long)(tau1 / TILES_PER_BATCH) * NN
                            + (long)(tau1 % TILES_PER_BATCH) * BMV;
            long ar = row1 + r;
            if (ar >= (long)TOT_ROWS) ar = TOT_ROWS - 1;
            const float* asrc = gnn + ar * HNF + (cq << 2);
            #pragma unroll
            for (int i = 0; i < 8; i++)
                fr[i] = *(const float4*)(asrc + (i << 5));
        }

        // ---- barrier-free MFMA loop: 8 k-steps x (4m x 2n) per wave ----
        float4v acc[4][2];
        #pragma unroll
        for (int m = 0; m < 4; m++)
            #pragma unroll
            for (int n = 0; n < 2; n++)
                acc[m][n] = (float4v){0.f, 0.f, 0.f, 0.f};

        #pragma unroll 2
        for (int kk = 0; kk < 8; ++kk) {
            short8 bf[2], af[4];
            #pragma unroll
            for (int n = 0; n < 2; n++) {
                int nf = (w << 1) + n;
                size_t off = (size_t)((((kk << 4) + nf) << 6) | l) << 3;
                bf[n] = *(const short8*)(B0p + off);
            }
            #pragma unroll
            for (int m = 0; m < 4; m++)
                af[m] = *(const short8*)(Abf + ((((kk << 2) + m) << 6) | l) * 8);
            #pragma unroll
            for (int m = 0; m < 4; m++)
                #pragma unroll
                for (int n = 0; n < 2; n++)
                    acc[m][n] = __builtin_amdgcn_mfma_f32_16x16x32_bf16(af[m], bf[n], acc[m][n], 0, 0, 0);
        }

        // ---- epilogue: bias+relu, e2 row-dots, emb partials ----
        // C frag: col = (2w+n)*16 + (l&15), row = m*16 + (l>>4)*4 + j
        float ps0[4][4], ps1[4][4], embp[2] = {0.f, 0.f};
        #pragma unroll
        for (int m = 0; m < 4; m++)
            #pragma unroll
            for (int j = 0; j < 4; j++) { ps0[m][j] = 0.f; ps1[m][j] = 0.f; }

        #pragma unroll
        for (int m = 0; m < 4; m++)
            #pragma unroll
            for (int n = 0; n < 2; n++)
                #pragma unroll
                for (int j = 0; j < 4; j++) {
                    float h = fmaxf(acc[m][n][j] + b1v[n], 0.f);
                    ps0[m][j] += h * w20[n];
                    ps1[m][j] += h * w21[n];
                    int row = (m << 4) + (fk << 2) + j;
                    if (row < BMV) embp[n] += h;     // exclude pad row
                }

        #pragma unroll
        for (int off = 1; off < 16; off <<= 1)
            #pragma unroll
            for (int m = 0; m < 4; m++)
                #pragma unroll
                for (int j = 0; j < 4; j++) {
                    ps0[m][j] += __shfl_xor(ps0[m][j], off);
                    ps1[m][j] += __shfl_xor(ps1[m][j], off);
                }
        if (frow == 0) {
            #pragma unroll
            for (int m = 0; m < 4; m++)
                #pragma unroll
                for (int j = 0; j < 4; j++) {
                    int row = (m << 4) + (fk << 2) + j;
                    red0[w][row] = ps0[m][j];
                    red1[w][row] = ps1[m][j];
                }
        }

        #pragma unroll
        for (int n = 0; n < 2; n++) {
            embp[n] += __shfl_xor(embp[n], 16);
            embp[n] += __shfl_xor(embp[n], 32);
        }
        {
            const int tb = tau / TILES_PER_BATCH;
            if (l < 16) {
                #pragma unroll
                for (int n = 0; n < 2; n++)
                    atomicAdd(emb + (size_t)tb * 256 + (((w << 1) + n) << 4) + l,
                              embp[n]);
            }
        }

        __syncthreads();
        if (t < BMV) {
            float v0 = b20, v1 = b21;
            #pragma unroll
            for (int ww = 0; ww < 8; ww++) { v0 += red0[ww][t]; v1 += red1[ww][t]; }
            Dreg[row0 + t] = v0;    // raw e2 ch0 (symmetrized in recon)
            Wreg[row0 + t] = v1;
        }
        // next tile's Abf writes are ordered after this barrier (in-order DS)
    }
}

// ---------------------------------------------------------------------------
// Kernel 2: fused symmetrize+softplus (writes D/W outputs) + register MDS
// recon. 1 block = 1 wave = 1 batch; lane i<21 owns row i. All wave-uniform
// broadcasts via readlane (SGPR), not ds_bpermute.
// ---------------------------------------------------------------------------
__global__ __launch_bounds__(64) void symrecon_kernel(
    float* __restrict__ Dreg, float* __restrict__ Wreg,
    const float* __restrict__ un, const float* __restrict__ xn,
    float* __restrict__ Xo)
{
    const int b = blockIdx.x, l = threadIdx.x;
    __shared__ float R0[NN], R1[NN];

    float* Db = Dreg + (size_t)b * NN;
    float* Wb = Wreg + (size_t)b * NN;
    for (int idx = l; idx < NN; idx += 64) { R0[idx] = Db[idx]; R1[idx] = Wb[idx]; }
    __syncthreads();

    const bool act = (l < NMAX);
    const int li = act ? l : 0;
    float Drow[NMAX], Wrow[NMAX];
    float rs = 0.f;
    #pragma unroll
    for (int q = 0; q < NMAX; q++) {
        float rd = R0[li * NMAX + q] + R0[q * NMAX + li];
        float rw = R1[li * NMAX + q] + R1[q * NMAX + li];
        float d = (q == li) ? 0.f : softplus_f(rd);
        float wv = softplus_f(rw);
        Drow[q] = act ? d : 0.f;
        Wrow[q] = act ? wv : 0.f;
        rs += Drow[q];
    }
    if (act) {
        #pragma unroll
        for (int q = 0; q < NMAX; q++) {
            Db[l * NMAX + q] = Drow[q];
            Wb[l * NMAX + q] = Wrow[q];
        }
    }

    // double-centering -> A rows in registers
    float tot = rs;
    #pragma unroll
    for (int m = 1; m < 64; m <<= 1) tot += __shfl_xor(tot, m);
    const float mean = tot * (1.f / (float)NN);
    const float rsn = rs * (1.f / (float)NMAX);
    float Arow[NMAX];
    #pragma unroll
    for (int q = 0; q < NMAX; q++) {
        float rsq = bcast(rsn, q);
        float v = -0.5f * (Drow[q] - rsn - rsq + mean);
        Arow[q] = act ? v : 0.f;
    }

    // deflated power iteration: k=3 eigvecs, 10 steps each
    float xr[3] = {0.f, 0.f, 0.f};
    #pragma unroll
    for (int e = 0; e < 3; e++) {
        float u = act ? un[(size_t)b * 63 + e * NMAX + l] : 0.f;
        for (int s = 0; s < 10; s++) {
            float n2 = u * u;
            #pragma unroll
            for (int m = 1; m < 64; m <<= 1) n2 += __shfl_xor(n2, m);
            u *= 1.f / fmaxf(sqrtf(n2), 1e-3f);
            float a = 0.f;
            #pragma unroll
            for (int q = 0; q < NMAX; q++) a = fmaf(Arow[q], bcast(u, q), a);
            u = act ? a : 0.f;
        }
        float e2 = u * u;
        #pragma unroll
        for (int m = 1; m < 64; m <<= 1) e2 += __shfl_xor(e2, m);
        u *= 1.f / sqrtf(sqrtf(e2 + 0.01f));
        xr[e] = u;
        #pragma unroll
        for (int q = 0; q < NMAX; q++) Arow[q] = fmaf(-u, bcast(u, q), Arow[q]);
    }
    float x = xr[0], y = xr[1], z = xr[2];
    if (act) {
        x += xn[(size_t)b * 63 + l * 3 + 0];
        y += xn[(size_t)b * 63 + l * 3 + 1];
        z += xn[(size_t)b * 63 + l * 3 + 2];
    }

    // 100 clipped gradient-descent steps (registers + readlane broadcasts)
    for (int tstep = 0; tstep < 100; tstep++) {
        float gx = 0.f, gy = 0.f, gz = 0.f;
        #pragma unroll
        for (int q = 0; q < NMAX; q++) {
            float dx = x - bcast(x, q);
            float dy = y - bcast(y, q);
            float dz = z - bcast(z, q);
            float s = fmaf(dx, dx, fmaf(dy, dy, fmaf(dz, dz, 0.01f)));
            float cm = Wrow[q] * (Drow[q] - s);
            gx = fmaf(cm, dx, gx);
            gy = fmaf(cm, dy, gy);
            gz = fmaf(cm, dz, gz);
        }
        float d0 = 0.8f * gx, d1 = 0.8f * gy, d2 = 0.8f * gz;
        float speed = sqrtf(fmaf(d0, d0, fmaf(d1, d1, fmaf(d2, d2, 1e-3f))));
        float alpha = 0.1f + 4.9f * (100.f - (float)tstep) * 0.01f;
        float scale = alpha * tanhf(speed / alpha) / speed;
        x = fmaf(d0, scale, x);
        y = fmaf(d1, scale, y);
        z = fmaf(d2, scale, z);
    }
    if (act) {
        Xo[(size_t)b * 63 + l * 3 + 0] = x;
        Xo[(size_t)b * 63 + l * 3 + 1] = y;
        Xo[(size_t)b * 63 + l * 3 + 2] = z;
    }
}

// ---------------------------------------------------------------------------
extern "C" void kernel_launch(void* const* d_in, const int* in_sizes, int n_in,
                              void* d_out, int out_size, void* d_ws, size_t ws_size,
                              hipStream_t stream) {
    const float* gnn = (const float*)d_in[0];
    const float* W1  = (const float*)d_in[1];
    const float* b1  = (const float*)d_in[2];
    const float* W2  = (const float*)d_in[3];
    const float* b2  = (const float*)d_in[4];
    const float* un  = (const float*)d_in[5];
    const float* xn  = (const float*)d_in[6];

    float* out  = (float*)d_out;
    float* Dreg = out;                                  // [1024*441]
    float* Wreg = out + (size_t)TOT_ROWS;               // [1024*441]
    float* emb  = out + (size_t)2 * TOT_ROWS;           // [1024*256]
    float* Xo   = out + (size_t)2 * TOT_ROWS + B_SZ*256;// [1024*63]

    short* B0p = (short*)d_ws;                          // 65536 bf16 (128KB)

    pack_w1<<<dim3(256), dim3(256), 0, stream>>>(W1, B0p);
    hipMemsetAsync(emb, 0, (size_t)B_SZ * 256 * sizeof(float), stream);

    fused_mlp_bf16<<<dim3(B_SZ * TILES_PER_BATCH / 2), dim3(512), 0, stream>>>(
        gnn, B0p, b1, W2, b2, Dreg, Wreg, emb);

    symrecon_kernel<<<dim3(B_SZ), dim3(64), 0, stream>>>(Dreg, Wreg, un, xn, Xo);
}

// Round 8
// 306.272 us; speedup vs baseline: 1.5939x; 1.5740x over previous
//
#include <hip/hip_runtime.h>
#include <hip/hip_bf16.h>
#include <math.h>

#define B_SZ 1024
#define NMAX 21
#define NN 441            // 21*21
#define HNF 256
#define TOT_ROWS (B_SZ * NN)   // 451584
#define TILES_PER_BATCH 7      // 441 = 7*63
#define BMV 63                 // valid rows per tile (row 63 is pad)

typedef short short8 __attribute__((ext_vector_type(8)));
typedef float float4v __attribute__((ext_vector_type(4)));

__device__ __forceinline__ float softplus_f(float x) {
    return fmaxf(x, 0.f) + log1pf(expf(-fabsf(x)));
}

__device__ __forceinline__ unsigned short f2bf(float x) {
    union { float f; unsigned int u; } v; v.f = x;
    unsigned int r = v.u + 0x7FFFu + ((v.u >> 16) & 1u);   // RNE
    return (unsigned short)(r >> 16);
}

// hardware packed fp32->bf16 (v_cvt_pk_bf16_f32), RNE
__device__ __forceinline__ unsigned pk_bf16(float lo, float hi) {
    __hip_bfloat162 h = __float22bfloat162_rn(float2{lo, hi});
    return *reinterpret_cast<unsigned*>(&h);
}

// wave-uniform broadcast of lane q via SGPR (readlane), avoids ds_bpermute
__device__ __forceinline__ float bcast(float v, int q) {
    int i = __builtin_amdgcn_readlane(__builtin_bit_cast(int, v), q);
    return __builtin_bit_cast(float, i);
}

// fast tanh for x>=0: 1 - 2/(exp2(x*2log2e)+1). v_exp/v_rcp approx (~1e-7).
__device__ __forceinline__ float tanh_fast(float x) {
    float e = __builtin_amdgcn_exp2f(x * 2.8853900817779268f);
    float q = __builtin_amdgcn_rcpf(e + 1.f);
    return fmaf(-2.f, q, 1.f);
}

// ---------------------------------------------------------------------------
// Pack W1 into MFMA B-fragment order as bf16 (+ zero emb, folded in).
// Fragment (kstep s 0..7, nfrag f 0..15): lane l, elem j holds
// W1[s*32 + (l>>4)*8 + j][f*16 + (l&15)].  Linear idx = ((s*16+f)*64+l)*8+j.
// ---------------------------------------------------------------------------
__global__ __launch_bounds__(256) void pack_w1(const float* __restrict__ W1,
                                               short* __restrict__ B0p,
                                               float* __restrict__ emb)
{
    int id = blockIdx.x * 256 + threadIdx.x;   // 0..65535
    int j = id & 7, l = (id >> 3) & 63, f = (id >> 9) & 15, s = id >> 13;
    int k = s * 32 + ((l >> 4) << 3) + j;
    int c = (f << 4) + (l & 15);
    B0p[id] = (short)f2bf(W1[k * HNF + c]);
    #pragma unroll
    for (int e = 0; e < 4; e++)
        emb[(size_t)e * 65536 + id] = 0.f;     // 4*65536 = 1024*256
}

// ---------------------------------------------------------------------------
// Kernel 1: 7168 blocks x 512 threads (8 waves), one 64x256 tile each.
// Stage: global_load_lds width-16 (async DMA, no VGPR round-trip) of raw fp32
// into 64KB LDS, with XOR-pre-swizzled per-lane SOURCE addresses so the
// convert pass reads bank-conflict-free (rule: linear dest + inv-swz source
// + swz read). Convert: each wave reads back only its own rows (8x
// ds_read_b128), cvt_pk to bf16, writes frag-linear into the first 32KB
// (overlay, barrier-separated). MFMA loop + fused epilogue as before.
// LDS 68KB -> 2 blocks/CU x 8 waves = 16 waves/CU.
// ---------------------------------------------------------------------------
__global__ __launch_bounds__(512, 4) void fused_mlp_bf16(
    const float* __restrict__ gnn, const short* __restrict__ B0p,
    const float* __restrict__ b1, const float* __restrict__ W2,
    const float* __restrict__ b2,
    float* __restrict__ Dreg, float* __restrict__ Wreg, float* __restrict__ emb)
{
    __shared__ __align__(16) char ldsbuf[65536];
    float* stage = (float*)ldsbuf;     // [64][256] fp32, cols xor-swizzled
    short* Abf   = (short*)ldsbuf;     // frag-linear bf16, overlays first 32KB
    __shared__ float red0[8][64];
    __shared__ float red1[8][64];

    const int t = threadIdx.x;
    const int w = t >> 6, l = t & 63;
    const int batch = blockIdx.x / TILES_PER_BATCH;
    const int tile  = blockIdx.x % TILES_PER_BATCH;
    const long row0 = (long)batch * NN + (long)tile * BMV;

    // ---- stage: wave w DMAs rows w*8 .. w*8+7, 1 KB (one row) per inst ----
    // physical LDS byte (r,pc*16) holds logical chunk (pc^ (r&7)) of row r
    #pragma unroll
    for (int i = 0; i < 8; i++) {
        int r = (w << 3) + i;
        long ar = row0 + r;
        if (ar >= (long)TOT_ROWS) ar = TOT_ROWS - 1;   // pad row clamp
        int j = (l & 56) | ((l ^ r) & 7);              // source 16B chunk
        const float* gsrc = gnn + ar * HNF + (j << 2);
        __builtin_amdgcn_global_load_lds(
            (const __attribute__((address_space(1))) unsigned*)gsrc,
            (__attribute__((address_space(3))) unsigned*)(stage + (r << 8)),
            16, 0, 0);
    }
    __syncthreads();   // vmcnt(0) drain + barrier

    // ---- convert: thread owns (row r = t>>3, kstep c = t&7) ----
    const int r = t >> 3, c = t & 7;
    float4 fr[8];
    #pragma unroll
    for (int i = 0; i < 8; i++) {
        int pc = (c << 3) + (i ^ (r & 7));             // physical chunk (swz read)
        fr[i] = *(const float4*)(stage + (r << 8) + (pc << 2));
    }
    __syncthreads();   // all fp32 reads done before bf16 overlay writes
    {
        const int mr = r >> 4;
        #pragma unroll
        for (int g = 0; g < 4; g++) {
            uint4 pv;
            pv.x = pk_bf16(fr[2*g].x,   fr[2*g].y);
            pv.y = pk_bf16(fr[2*g].z,   fr[2*g].w);
            pv.z = pk_bf16(fr[2*g+1].x, fr[2*g+1].y);
            pv.w = pk_bf16(fr[2*g+1].z, fr[2*g+1].w);
            int di = (((c << 2) + mr) << 6) + (g << 4) + (r & 15); // frag slot
            *(uint4*)(Abf + ((size_t)di << 3)) = pv;
        }
    }
    __syncthreads();

    // fragment decode for compute
    const int frow = l & 15;
    const int fk   = l >> 4;

    // ---- barrier-free MFMA loop: 8 k-steps x (4m x 2n) per wave ----
    float4v acc[4][2];
    #pragma unroll
    for (int m = 0; m < 4; m++)
        #pragma unroll
        for (int n = 0; n < 2; n++)
            acc[m][n] = (float4v){0.f, 0.f, 0.f, 0.f};

    #pragma unroll 2
    for (int kk = 0; kk < 8; ++kk) {
        short8 bf[2], af[4];
        #pragma unroll
        for (int n = 0; n < 2; n++) {
            int nf = (w << 1) + n;
            size_t off = (size_t)((((kk << 4) + nf) << 6) | l) << 3;
            bf[n] = *(const short8*)(B0p + off);
        }
        #pragma unroll
        for (int m = 0; m < 4; m++)
            af[m] = *(const short8*)(Abf + (size_t)((((kk << 2) + m) << 6) | l) * 8);
        #pragma unroll
        for (int m = 0; m < 4; m++)
            #pragma unroll
            for (int n = 0; n < 2; n++)
                acc[m][n] = __builtin_amdgcn_mfma_f32_16x16x32_bf16(af[m], bf[n], acc[m][n], 0, 0, 0);
    }

    // ---- epilogue: bias+relu, e2 row-dots, emb partials ----
    // C frag: col = (2w+n)*16 + (l&15), row = m*16 + (l>>4)*4 + j
    float w20[2], w21[2], b1v[2];
    #pragma unroll
    for (int n = 0; n < 2; n++) {
        int cc = (((w << 1) + n) << 4) + frow;
        b1v[n] = b1[cc];
        w20[n] = W2[2 * cc];
        w21[n] = W2[2 * cc + 1];
    }
    float ps0[4][4], ps1[4][4], embp[2] = {0.f, 0.f};
    #pragma unroll
    for (int m = 0; m < 4; m++)
        #pragma unroll
        for (int j = 0; j < 4; j++) { ps0[m][j] = 0.f; ps1[m][j] = 0.f; }

    #pragma unroll
    for (int m = 0; m < 4; m++)
        #pragma unroll
        for (int n = 0; n < 2; n++)
            #pragma unroll
            for (int j = 0; j < 4; j++) {
                float h = fmaxf(acc[m][n][j] + b1v[n], 0.f);
                ps0[m][j] += h * w20[n];
                ps1[m][j] += h * w21[n];
                int row = (m << 4) + (fk << 2) + j;
                if (row < BMV) embp[n] += h;     // exclude pad row
            }

    #pragma unroll
    for (int off = 1; off < 16; off <<= 1)
        #pragma unroll
        for (int m = 0; m < 4; m++)
            #pragma unroll
            for (int j = 0; j < 4; j++) {
                ps0[m][j] += __shfl_xor(ps0[m][j], off);
                ps1[m][j] += __shfl_xor(ps1[m][j], off);
            }
    if (frow == 0) {
        #pragma unroll
        for (int m = 0; m < 4; m++)
            #pragma unroll
            for (int j = 0; j < 4; j++) {
                int row = (m << 4) + (fk << 2) + j;
                red0[w][row] = ps0[m][j];
                red1[w][row] = ps1[m][j];
            }
    }

    #pragma unroll
    for (int n = 0; n < 2; n++) {
        embp[n] += __shfl_xor(embp[n], 16);
        embp[n] += __shfl_xor(embp[n], 32);
    }
    if (l < 16) {
        #pragma unroll
        for (int n = 0; n < 2; n++)
            atomicAdd(emb + (size_t)batch * 256 + (((w << 1) + n) << 4) + l, embp[n]);
    }

    __syncthreads();
    if (t < BMV) {
        float v0 = b2[0], v1 = b2[1];
        #pragma unroll
        for (int ww = 0; ww < 8; ww++) { v0 += red0[ww][t]; v1 += red1[ww][t]; }
        Dreg[row0 + t] = v0;    // raw e2 ch0 (symmetrized in recon)
        Wreg[row0 + t] = v1;
    }
}

// ---------------------------------------------------------------------------
// Kernel 2: fused symmetrize+softplus (writes D/W outputs) + register MDS
// recon. 1 block = 1 wave = 1 batch; lane i<21 owns row i. readlane
// broadcasts; 3-way split accumulators; W*D prefold; raw rsq/exp/rcp.
// ---------------------------------------------------------------------------
__global__ __launch_bounds__(64) void symrecon_kernel(
    float* __restrict__ Dreg, float* __restrict__ Wreg,
    const float* __restrict__ un, const float* __restrict__ xn,
    float* __restrict__ Xo)
{
    const int b = blockIdx.x, l = threadIdx.x;
    __shared__ float R0[NN], R1[NN];

    float* Db = Dreg + (size_t)b * NN;
    float* Wb = Wreg + (size_t)b * NN;
    for (int idx = l; idx < NN; idx += 64) { R0[idx] = Db[idx]; R1[idx] = Wb[idx]; }
    __syncthreads();

    const bool act = (l < NMAX);
    const int li = act ? l : 0;
    float Drow[NMAX], Wrow[NMAX], WD[NMAX];
    float rs = 0.f;
    #pragma unroll
    for (int q = 0; q < NMAX; q++) {
        float rd = R0[li * NMAX + q] + R0[q * NMAX + li];
        float rw = R1[li * NMAX + q] + R1[q * NMAX + li];
        float d = (q == li) ? 0.f : softplus_f(rd);
        float wv = softplus_f(rw);
        Drow[q] = act ? d : 0.f;
        Wrow[q] = act ? wv : 0.f;
        WD[q] = Wrow[q] * Drow[q];
        rs += Drow[q];
    }
    if (act) {
        #pragma unroll
        for (int q = 0; q < NMAX; q++) {
            Db[l * NMAX + q] = Drow[q];
            Wb[l * NMAX + q] = Wrow[q];
        }
    }

    // double-centering (lanes >=21 hold zeros; 5-step butterfly within 32
    // suffices for lanes 0..20 since lanes 21..31 are zero)
    float tot = rs;
    #pragma unroll
    for (int m = 1; m < 32; m <<= 1) tot += __shfl_xor(tot, m);
    const float mean = tot * (1.f / (float)NN);
    const float rsn = rs * (1.f / (float)NMAX);
    float Arow[NMAX];
    #pragma unroll
    for (int q = 0; q < NMAX; q++) {
        float rsq = bcast(rsn, q);
        float v = -0.5f * (Drow[q] - rsn - rsq + mean);
        Arow[q] = act ? v : 0.f;
    }

    // deflated power iteration: k=3 eigvecs, 10 steps each
    float xr[3] = {0.f, 0.f, 0.f};
    #pragma unroll
    for (int e = 0; e < 3; e++) {
        float u = act ? un[(size_t)b * 63 + e * NMAX + l] : 0.f;
        for (int s = 0; s < 10; s++) {
            float n2 = u * u;
            #pragma unroll
            for (int m = 1; m < 32; m <<= 1) n2 += __shfl_xor(n2, m);
            // 1/max(sqrt(n2),1e-3) == min(rsq(n2), 1000)
            u *= fminf(__builtin_amdgcn_rsqf(n2), 1000.f);
            float a0 = 0.f, a1 = 0.f, a2 = 0.f;
            #pragma unroll
            for (int q = 0; q < NMAX; q++) {
                float uq = bcast(u, q);
                if ((q % 3) == 0)      a0 = fmaf(Arow[q], uq, a0);
                else if ((q % 3) == 1) a1 = fmaf(Arow[q], uq, a1);
                else                   a2 = fmaf(Arow[q], uq, a2);
            }
            u = act ? ((a0 + a1) + a2) : 0.f;
        }
        float e2 = u * u;
        #pragma unroll
        for (int m = 1; m < 32; m <<= 1) e2 += __shfl_xor(e2, m);
        u *= sqrtf(__builtin_amdgcn_rsqf(e2 + 0.01f));   // (e2+.01)^-0.25
        xr[e] = u;
        #pragma unroll
        for (int q = 0; q < NMAX; q++) Arow[q] = fmaf(-u, bcast(u, q), Arow[q]);
    }
    float x = xr[0], y = xr[1], z = xr[2];
    if (act) {
        x += xn[(size_t)b * 63 + l * 3 + 0];
        y += xn[(size_t)b * 63 + l * 3 + 1];
        z += xn[(size_t)b * 63 + l * 3 + 2];
    }

    // 100 clipped GD steps: registers + readlane; split accumulators (ILP)
    for (int tstep = 0; tstep < 100; tstep++) {
        float gx0=0.f,gx1=0.f,gx2=0.f, gy0=0.f,gy1=0.f,gy2=0.f,
              gz0=0.f,gz1=0.f,gz2=0.f;
        #pragma unroll
        for (int q = 0; q < NMAX; q++) {
            float dx = x - bcast(x, q);
            float dy = y - bcast(y, q);
            float dz = z - bcast(z, q);
            float s = fmaf(dx, dx, fmaf(dy, dy, fmaf(dz, dz, 0.01f)));
            float cm = fmaf(-Wrow[q], s, WD[q]);   // W*(D - s)
            if ((q % 3) == 0)      { gx0 = fmaf(cm,dx,gx0); gy0 = fmaf(cm,dy,gy0); gz0 = fmaf(cm,dz,gz0); }
            else if ((q % 3) == 1) { gx1 = fmaf(cm,dx,gx1); gy1 = fmaf(cm,dy,gy1); gz1 = fmaf(cm,dz,gz1); }
            else                   { gx2 = fmaf(cm,dx,gx2); gy2 = fmaf(cm,dy,gy2); gz2 = fmaf(cm,dz,gz2); }
        }
        float d0 = 0.8f * ((gx0 + gx1) + gx2);
        float d1 = 0.8f * ((gy0 + gy1) + gy2);
        float d2 = 0.8f * ((gz0 + gz1) + gz2);
        float ss = fmaf(d0, d0, fmaf(d1, d1, fmaf(d2, d2, 1e-3f)));
        float inv_sp = __builtin_amdgcn_rsqf(ss);
        float speed  = ss * inv_sp;
        float alpha  = fmaf(-0.049f, (float)tstep, 5.0f);
        float th     = tanh_fast(speed * __builtin_amdgcn_rcpf(alpha));
        float scale  = alpha * th * inv_sp;
        x = fmaf(d0, scale, x);
        y = fmaf(d1, scale, y);
        z = fmaf(d2, scale, z);
    }
    if (act) {
        Xo[(size_t)b * 63 + l * 3 + 0] = x;
        Xo[(size_t)b * 63 + l * 3 + 1] = y;
        Xo[(size_t)b * 63 + l * 3 + 2] = z;
    }
}

// ---------------------------------------------------------------------------
extern "C" void kernel_launch(void* const* d_in, const int* in_sizes, int n_in,
                              void* d_out, int out_size, void* d_ws, size_t ws_size,
                              hipStream_t stream) {
    const float* gnn = (const float*)d_in[0];
    const float* W1  = (const float*)d_in[1];
    const float* b1  = (const float*)d_in[2];
    const float* W2  = (const float*)d_in[3];
    const float* b2  = (const float*)d_in[4];
    const float* un  = (const float*)d_in[5];
    const float* xn  = (const float*)d_in[6];

    float* out  = (float*)d_out;
    float* Dreg = out;                                  // [1024*441]
    float* Wreg = out + (size_t)TOT_ROWS;               // [1024*441]
    float* emb  = out + (size_t)2 * TOT_ROWS;           // [1024*256]
    float* Xo   = out + (size_t)2 * TOT_ROWS + B_SZ*256;// [1024*63]

    short* B0p = (short*)d_ws;                          // 65536 bf16 (128KB)

    pack_w1<<<dim3(256), dim3(256), 0, stream>>>(W1, B0p, emb);

    fused_mlp_bf16<<<dim3(B_SZ * TILES_PER_BATCH), dim3(512), 0, stream>>>(
        gnn, B0p, b1, W2, b2, Dreg, Wreg, emb);

    symrecon_kernel<<<dim3(B_SZ), dim3(64), 0, stream>>>(Dreg, Wreg, un, xn, Xo);
}